// Round 1
// baseline (336.232 us; speedup 1.0000x reference)
//
#include <hip/hip_runtime.h>
#include <math.h>

constexpr int IMH = 2048, IMW = 2048, NB = 4;
constexpr int NPIX = NB * IMH * IMW;           // 16777216
constexpr unsigned KSEL = 8388607u;            // floor(0.5*(NPIX-1)) -> quantile 'lower' index

// ---------- helpers ----------
__device__ __forceinline__ unsigned f2u(float f) {
    unsigned b = __float_as_uint(f);
    return (b & 0x80000000u) ? ~b : (b | 0x80000000u);   // monotone float->uint
}

__device__ __forceinline__ void gauss7(float* a) {
    // matches _gaussian_kernel(7, 5.0): g1=exp(-ax^2/50) (double), separable factor g1/sum
    double g[7]; double s = 0.0;
    #pragma unroll
    for (int i = 0; i < 7; ++i) { double ax = (double)(i - 3); g[i] = exp(-ax * ax / 50.0); s += g[i]; }
    #pragma unroll
    for (int i = 0; i < 7; ++i) a[i] = (float)(g[i] / s);
}

// ---------- K1: fused Sobel + products + separable 7x7 Gaussian + R ----------
// tile 64x64 outputs, x halo 4 (sobel 1 + gauss 3), product halo 3
__launch_bounds__(256, 2)
__global__ void harris_R(const float* __restrict__ x, float* __restrict__ Rout) {
    __shared__ float smem[5184 + 4900 + 4900 + 4480];   // 77856 B
    float* SX  = smem;              // 72x72 x tile (stride 72)
    float* SIX = smem + 5184;       // 70x70 Ix
    float* SIY = SIX + 4900;        // 70x70 Iy
    float* STH = SIY + 4900;        // 70x64 horizontal-blur
    float* SP  = SX;                // 70x70 product (aliases SX; x dead by then)

    const int tid = threadIdx.x;
    const int x0 = blockIdx.x * 64, y0 = blockIdx.y * 64, b = blockIdx.z;
    const float* xb = x + (size_t)b * IMH * IMW;

    // load x tile + halo 4, zero outside image (sobel zero-padding)
    for (int i = tid; i < 72 * 72; i += 256) {
        int r = i / 72, c = i - r * 72;
        int gy = y0 - 4 + r, gx = x0 - 4 + c;
        float v = 0.0f;
        if ((unsigned)gy < (unsigned)IMH && (unsigned)gx < (unsigned)IMW) v = xb[gy * IMW + gx];
        SX[i] = v;
    }
    __syncthreads();

    // Sobel over 70x70 (image coords y0-3+r, x0-3+c); products are ZERO outside image
    for (int i = tid; i < 70 * 70; i += 256) {
        int r = i / 70, c = i - r * 70;
        int gy = y0 - 3 + r, gx = x0 - 3 + c;
        float ix = 0.0f, iy = 0.0f;
        if ((unsigned)gy < (unsigned)IMH && (unsigned)gx < (unsigned)IMW) {
            const float* p = SX + r * 72 + c;   // p points at x[gy-1][gx-1]
            float x00 = p[0],   x01 = p[1],   x02 = p[2];
            float x10 = p[72],                 x12 = p[74];
            float x20 = p[144], x21 = p[145], x22 = p[146];
            ix = (x02 + 2.0f * x12 + x22) - (x00 + 2.0f * x10 + x20);
            iy = (x20 + 2.0f * x21 + x22) - (x00 + 2.0f * x01 + x02);
        }
        SIX[i] = ix; SIY[i] = iy;
    }
    __syncthreads();

    float a[7]; gauss7(a);
    const int lx = tid & 63, rb = tid >> 6;
    float Sacc[3][16];

    #pragma unroll
    for (int ch = 0; ch < 3; ++ch) {
        for (int i = tid; i < 70 * 70; i += 256) {
            float ix = SIX[i], iy = SIY[i];
            SP[i] = (ch == 0) ? ix * ix : (ch == 1) ? iy * iy : ix * iy;
        }
        __syncthreads();
        for (int i = tid; i < 70 * 64; i += 256) {
            int r = i >> 6, c = i & 63;
            const float* p = SP + r * 70 + c;
            float s = 0.0f;
            #pragma unroll
            for (int d = 0; d < 7; ++d) s += a[d] * p[d];
            STH[i] = s;
        }
        __syncthreads();
        #pragma unroll
        for (int k = 0; k < 16; ++k) {
            int r = rb + 4 * k;
            float s = 0.0f;
            #pragma unroll
            for (int d = 0; d < 7; ++d) s += a[d] * STH[(r + d) * 64 + lx];
            Sacc[ch][k] = s;
        }
        __syncthreads();
    }

    float* Rb = Rout + (size_t)b * IMH * IMW;
    #pragma unroll
    for (int k = 0; k < 16; ++k) {
        int r = rb + 4 * k;
        float sxx = Sacc[0][k], syy = Sacc[1][k], sxy = Sacc[2][k];
        float tr = sxx + syy;
        float R = sxx * syy - sxy * sxy - 0.05f * tr * tr;
        Rb[(size_t)(y0 + r) * IMW + (x0 + lx)] = R;
    }
}

// ---------- median: 3-pass radix select (12 + 12 + 8 bits) ----------
__global__ void zero_kernel(unsigned* __restrict__ p, int n, int kidx, unsigned kval) {
    int i = blockIdx.x * blockDim.x + threadIdx.x;
    if (i < n) p[i] = (i == kidx) ? kval : 0u;
}

__global__ void hist1_kernel(const float* __restrict__ R, unsigned* __restrict__ hist) {
    __shared__ unsigned lh[4096];
    for (int i = threadIdx.x; i < 4096; i += 256) lh[i] = 0u;
    __syncthreads();
    const float4* R4 = (const float4*)R;
    const int n4 = NPIX / 4;
    for (int i = blockIdx.x * 256 + threadIdx.x; i < n4; i += gridDim.x * 256) {
        float4 v = R4[i];
        atomicAdd(&lh[f2u(v.x) >> 20], 1u);
        atomicAdd(&lh[f2u(v.y) >> 20], 1u);
        atomicAdd(&lh[f2u(v.z) >> 20], 1u);
        atomicAdd(&lh[f2u(v.w) >> 20], 1u);
    }
    __syncthreads();
    for (int i = threadIdx.x; i < 4096; i += 256) { unsigned c = lh[i]; if (c) atomicAdd(&hist[i], c); }
}

__global__ void hist2_kernel(const float* __restrict__ R, unsigned* __restrict__ hist,
                             const unsigned* __restrict__ sel) {
    __shared__ unsigned lh[4096];
    for (int i = threadIdx.x; i < 4096; i += 256) lh[i] = 0u;
    __syncthreads();
    const unsigned pref = sel[1];
    const float4* R4 = (const float4*)R;
    const int n4 = NPIX / 4;
    for (int i = blockIdx.x * 256 + threadIdx.x; i < n4; i += gridDim.x * 256) {
        float4 v = R4[i];
        unsigned u;
        u = f2u(v.x); if ((u >> 20) == pref) atomicAdd(&lh[(u >> 8) & 0xFFFu], 1u);
        u = f2u(v.y); if ((u >> 20) == pref) atomicAdd(&lh[(u >> 8) & 0xFFFu], 1u);
        u = f2u(v.z); if ((u >> 20) == pref) atomicAdd(&lh[(u >> 8) & 0xFFFu], 1u);
        u = f2u(v.w); if ((u >> 20) == pref) atomicAdd(&lh[(u >> 8) & 0xFFFu], 1u);
    }
    __syncthreads();
    for (int i = threadIdx.x; i < 4096; i += 256) { unsigned c = lh[i]; if (c) atomicAdd(&hist[i], c); }
}

__global__ void hist3_kernel(const float* __restrict__ R, unsigned* __restrict__ hist,
                             const unsigned* __restrict__ sel) {
    __shared__ unsigned lh[256];
    if (threadIdx.x < 256) lh[threadIdx.x] = 0u;
    __syncthreads();
    const unsigned pref = sel[1];
    const float4* R4 = (const float4*)R;
    const int n4 = NPIX / 4;
    for (int i = blockIdx.x * 256 + threadIdx.x; i < n4; i += gridDim.x * 256) {
        float4 v = R4[i];
        unsigned u;
        u = f2u(v.x); if ((u >> 8) == pref) atomicAdd(&lh[u & 0xFFu], 1u);
        u = f2u(v.y); if ((u >> 8) == pref) atomicAdd(&lh[u & 0xFFu], 1u);
        u = f2u(v.z); if ((u >> 8) == pref) atomicAdd(&lh[u & 0xFFu], 1u);
        u = f2u(v.w); if ((u >> 8) == pref) atomicAdd(&lh[u & 0xFFu], 1u);
    }
    __syncthreads();
    { unsigned c = lh[threadIdx.x]; if (c) atomicAdd(&hist[threadIdx.x], c); }
}

// sel[0]=k_remaining, sel[1]=prefix; sel[2] (as float) = median once final
__global__ void select_kernel(const unsigned* __restrict__ hist, unsigned* __restrict__ sel,
                              int nbins, int bits, int final_stage) {
    __shared__ unsigned part[256];
    const int t = threadIdx.x;
    const int bpt = nbins >> 8;
    const unsigned krem = sel[0];
    unsigned s = 0;
    for (int i = 0; i < bpt; ++i) s += hist[t * bpt + i];
    part[t] = s;
    __syncthreads();
    if (t == 0) {
        unsigned run = 0; int ch = 255;
        for (int i = 0; i < 256; ++i) { if (run + part[i] > krem) { ch = i; break; } run += part[i]; }
        int bsel = ch * bpt; unsigned r2 = run;
        for (int j = ch * bpt; j < (ch + 1) * bpt; ++j) {
            if (r2 + hist[j] > krem) { bsel = j; break; }
            r2 += hist[j];
        }
        sel[0] = krem - r2;
        unsigned pref = (sel[1] << bits) | (unsigned)bsel;
        sel[1] = pref;
        if (final_stage) {
            unsigned fb = (pref & 0x80000000u) ? (pref ^ 0x80000000u) : ~pref;
            ((float*)sel)[2] = __uint_as_float(fb);
        }
    }
}

// ---------- K2: threshold + 7x7 maxpool (separable) + binarize*R ----------
__launch_bounds__(256, 4)
__global__ void harris_out(const float* __restrict__ R, const unsigned* __restrict__ sel,
                           float* __restrict__ out) {
    __shared__ float SR[70 * 72];   // raw R with halo 3, OOB = -inf (stride 72)
    __shared__ float SM[70 * 64];   // horizontal thr-max
    const float med = ((const float*)sel)[2];
    const int tid = threadIdx.x;
    const int x0 = blockIdx.x * 64, y0 = blockIdx.y * 64, b = blockIdx.z;
    const float* Rb = R + (size_t)b * IMH * IMW;

    for (int i = tid; i < 70 * 70; i += 256) {
        int r = i / 70, c = i - r * 70;
        int gy = y0 - 3 + r, gx = x0 - 3 + c;
        float v = -INFINITY;
        if ((unsigned)gy < (unsigned)IMH && (unsigned)gx < (unsigned)IMW) v = Rb[gy * IMW + gx];
        SR[r * 72 + c] = v;
    }
    __syncthreads();

    for (int i = tid; i < 70 * 64; i += 256) {
        int r = i >> 6, c = i & 63;
        const float* p = SR + r * 72 + c;
        float m = -INFINITY;
        #pragma unroll
        for (int d = 0; d < 7; ++d) {
            float v = p[d];
            float t = (v < med) ? ((v == -INFINITY) ? -INFINITY : 0.0f) : v;  // thr, OOB stays -inf
            m = fmaxf(m, t);
        }
        SM[i] = m;
    }
    __syncthreads();

    const int lx = tid & 63, rb = tid >> 6;
    float* ob = out + (size_t)b * IMH * IMW;
    #pragma unroll
    for (int k = 0; k < 16; ++k) {
        int r = rb + 4 * k;
        float pooled = -INFINITY;
        #pragma unroll
        for (int d = 0; d < 7; ++d) pooled = fmaxf(pooled, SM[(r + d) * 64 + lx]);
        float v = SR[(r + 3) * 72 + (lx + 3)];       // center raw R (always in-bounds)
        float t = (v < med) ? 0.0f : v;              // identical bits to SM-side thr for center
        ob[(size_t)(y0 + r) * IMW + (x0 + lx)] = (t == pooled) ? v : 0.0f;
    }
}

extern "C" void kernel_launch(void* const* d_in, const int* in_sizes, int n_in,
                              void* d_out, int out_size, void* d_ws, size_t ws_size,
                              hipStream_t stream) {
    const float* x = (const float*)d_in[0];
    float* out = (float*)d_out;

    // ws layout: R (64MB) | h1[4096] | h2[4096] | h3[256] | sel[8]
    const size_t needed = (size_t)NPIX * 4 + (4096 + 4096 + 256 + 8) * 4;
    if (ws_size < needed) return;
    float* R = (float*)d_ws;
    unsigned* hbase = (unsigned*)((char*)d_ws + (size_t)NPIX * 4);
    unsigned* h1 = hbase;
    unsigned* h2 = hbase + 4096;
    unsigned* h3 = hbase + 8192;
    unsigned* sel = hbase + 8448;

    zero_kernel<<<(8456 + 255) / 256, 256, 0, stream>>>(hbase, 8456, 8448, KSEL);

    dim3 tgrid(IMW / 64, IMH / 64, NB);
    harris_R<<<tgrid, 256, 0, stream>>>(x, R);

    hist1_kernel<<<2048, 256, 0, stream>>>(R, h1);
    select_kernel<<<1, 256, 0, stream>>>(h1, sel, 4096, 12, 0);
    hist2_kernel<<<2048, 256, 0, stream>>>(R, h2, sel);
    select_kernel<<<1, 256, 0, stream>>>(h2, sel, 4096, 12, 0);
    hist3_kernel<<<2048, 256, 0, stream>>>(R, h3, sel);
    select_kernel<<<1, 256, 0, stream>>>(h3, sel, 256, 8, 1);

    harris_out<<<tgrid, 256, 0, stream>>>(R, sel, out);
}

// Round 2
// 286.499 us; speedup vs baseline: 1.1736x; 1.1736x over previous
//
#include <hip/hip_runtime.h>
#include <math.h>

constexpr int IMH = 2048, IMW = 2048, NB = 4;
constexpr int NPIX = NB * IMH * IMW;           // 16777216
constexpr unsigned KSEL = 8388607u;            // floor(0.5*(NPIX-1)) -> quantile 'lower' index

// ---------- helpers ----------
__device__ __forceinline__ unsigned f2u(float f) {
    unsigned b = __float_as_uint(f);
    return (b & 0x80000000u) ? ~b : (b | 0x80000000u);   // monotone float->uint
}

__device__ __forceinline__ void gauss7(float* a) {
    // exp(-k^2/50) for k=1..3 as exact double literals (matches np.float64 path)
    const double g0 = 0.8352702114112720;   // exp(-0.18)
    const double g1 = 0.9231163463866358;   // exp(-0.08)
    const double g2 = 0.9801986733067553;   // exp(-0.02)
    const double s = 2.0 * (g0 + g1 + g2) + 1.0;
    const double inv = 1.0 / s;
    a[0] = a[6] = (float)(g0 * inv);
    a[1] = a[5] = (float)(g1 * inv);
    a[2] = a[4] = (float)(g2 * inv);
    a[3] = (float)inv;
}

// ---------- K1: fused Sobel + products + separable 7x7 Gaussian + R + hist1 ----------
// tile 64 wide x 32 tall. LDS (floats):
//   [0, 7296)      STH 38x192 (3ch interleaved); first 2880 double as SX 40x72
//   [7296, 12616)  SIXY 38x140 (ix,iy interleaved); doubles as 4096-bin hist later
__launch_bounds__(256, 3)
__global__ void harris_R(const float* __restrict__ x, float* __restrict__ Rout,
                         unsigned* __restrict__ hist) {
    __shared__ float smem[12616];   // 50464 B
    float* SX   = smem;             // 40x72
    float* STH  = smem;             // 38x192
    float* SIXY = smem + 7296;      // 38x140
    unsigned* LH = (unsigned*)(smem + 7296);

    const int tid = threadIdx.x;
    const int x0 = blockIdx.x * 64, y0 = blockIdx.y * 32, b = blockIdx.z;
    const float* xb = x + (size_t)b * IMH * IMW;

    // load x tile 40x72 (halo 4), zero outside image
    for (int i = tid; i < 40 * 72; i += 256) {
        int r = i / 72, c = i - r * 72;
        int gy = y0 - 4 + r, gx = x0 - 4 + c;
        float v = 0.0f;
        if ((unsigned)gy < (unsigned)IMH && (unsigned)gx < (unsigned)IMW) v = xb[(size_t)gy * IMW + gx];
        SX[i] = v;
    }
    __syncthreads();

    // Sobel 38x70 -> SIXY; zero outside image (product zero-padding semantics)
    for (int i = tid; i < 38 * 70; i += 256) {
        int r = i / 70, c = i - r * 70;
        int gy = y0 - 3 + r, gx = x0 - 3 + c;
        float ix = 0.0f, iy = 0.0f;
        if ((unsigned)gy < (unsigned)IMH && (unsigned)gx < (unsigned)IMW) {
            const float* p = SX + r * 72 + c;   // x[gy-1][gx-1]
            float x00 = p[0],   x01 = p[1],   x02 = p[2];
            float x10 = p[72],                 x12 = p[74];
            float x20 = p[144], x21 = p[145], x22 = p[146];
            ix = (x02 + 2.0f * x12 + x22) - (x00 + 2.0f * x10 + x20);
            iy = (x20 + 2.0f * x21 + x22) - (x00 + 2.0f * x01 + x02);
        }
        SIXY[r * 140 + c * 2]     = ix;
        SIXY[r * 140 + c * 2 + 1] = iy;
    }
    __syncthreads();

    float a[7]; gauss7(a);

    // hblur, all 3 channels fused, products computed inline: 38x64 -> STH (aliases dead SX)
    for (int i = tid; i < 38 * 64; i += 256) {
        int r = i >> 6, c = i & 63;
        const float* p = SIXY + r * 140 + c * 2;
        float sxx = 0.f, syy = 0.f, sxy = 0.f;
        #pragma unroll
        for (int d = 0; d < 7; ++d) {
            float ix = p[2 * d], iy = p[2 * d + 1];
            float t = a[d] * ix;
            sxx += t * ix;
            sxy += t * iy;
            syy += (a[d] * iy) * iy;
        }
        float* q = STH + r * 192 + c * 3;
        q[0] = sxx; q[1] = syy; q[2] = sxy;
    }
    __syncthreads();

    // SIXY now dead: zero the LDS histogram while doing vblur
    for (int i = tid; i < 4096; i += 256) LH[i] = 0u;

    const int lx = tid & 63, rb = tid >> 6;
    float* Rb = Rout + (size_t)b * IMH * IMW;
    float rv[8];
    #pragma unroll
    for (int k = 0; k < 8; ++k) {
        int ro = rb + 4 * k;
        float sxx = 0.f, syy = 0.f, sxy = 0.f;
        #pragma unroll
        for (int d = 0; d < 7; ++d) {
            const float* q = STH + (ro + d) * 192 + lx * 3;
            sxx += a[d] * q[0];
            syy += a[d] * q[1];
            sxy += a[d] * q[2];
        }
        float tr = sxx + syy;
        float R = sxx * syy - sxy * sxy - 0.05f * tr * tr;
        rv[k] = R;
        Rb[(size_t)(y0 + ro) * IMW + (x0 + lx)] = R;
    }
    __syncthreads();   // hist zeroing complete

    #pragma unroll
    for (int k = 0; k < 8; ++k) atomicAdd(&LH[f2u(rv[k]) >> 20], 1u);
    __syncthreads();

    for (int i = tid; i < 4096; i += 256) { unsigned c = LH[i]; if (c) atomicAdd(&hist[i], c); }
}

// ---------- median: 3-pass radix select (12 + 12 + 8 bits); pass 1 fused above ----------
__global__ void zero_kernel(unsigned* __restrict__ p, int n, int kidx, unsigned kval) {
    int i = blockIdx.x * blockDim.x + threadIdx.x;
    if (i < n) p[i] = (i == kidx) ? kval : 0u;
}

__global__ void hist2_kernel(const float* __restrict__ R, unsigned* __restrict__ hist,
                             const unsigned* __restrict__ sel) {
    __shared__ unsigned lh[4096];
    for (int i = threadIdx.x; i < 4096; i += 256) lh[i] = 0u;
    __syncthreads();
    const unsigned pref = sel[1];
    const float4* R4 = (const float4*)R;
    const int n4 = NPIX / 4;
    for (int i = blockIdx.x * 256 + threadIdx.x; i < n4; i += gridDim.x * 256) {
        float4 v = R4[i];
        unsigned u;
        u = f2u(v.x); if ((u >> 20) == pref) atomicAdd(&lh[(u >> 8) & 0xFFFu], 1u);
        u = f2u(v.y); if ((u >> 20) == pref) atomicAdd(&lh[(u >> 8) & 0xFFFu], 1u);
        u = f2u(v.z); if ((u >> 20) == pref) atomicAdd(&lh[(u >> 8) & 0xFFFu], 1u);
        u = f2u(v.w); if ((u >> 20) == pref) atomicAdd(&lh[(u >> 8) & 0xFFFu], 1u);
    }
    __syncthreads();
    for (int i = threadIdx.x; i < 4096; i += 256) { unsigned c = lh[i]; if (c) atomicAdd(&hist[i], c); }
}

__global__ void hist3_kernel(const float* __restrict__ R, unsigned* __restrict__ hist,
                             const unsigned* __restrict__ sel) {
    __shared__ unsigned lh[256];
    if (threadIdx.x < 256) lh[threadIdx.x] = 0u;
    __syncthreads();
    const unsigned pref = sel[1];
    const float4* R4 = (const float4*)R;
    const int n4 = NPIX / 4;
    for (int i = blockIdx.x * 256 + threadIdx.x; i < n4; i += gridDim.x * 256) {
        float4 v = R4[i];
        unsigned u;
        u = f2u(v.x); if ((u >> 8) == pref) atomicAdd(&lh[u & 0xFFu], 1u);
        u = f2u(v.y); if ((u >> 8) == pref) atomicAdd(&lh[u & 0xFFu], 1u);
        u = f2u(v.z); if ((u >> 8) == pref) atomicAdd(&lh[u & 0xFFu], 1u);
        u = f2u(v.w); if ((u >> 8) == pref) atomicAdd(&lh[u & 0xFFu], 1u);
    }
    __syncthreads();
    { unsigned c = lh[threadIdx.x]; if (c) atomicAdd(&hist[threadIdx.x], c); }
}

// sel[0]=k_remaining, sel[1]=prefix; sel[2] (as float) = median once final
__global__ void select_kernel(const unsigned* __restrict__ hist, unsigned* __restrict__ sel,
                              int bpt, int bits, int final_stage) {
    __shared__ unsigned part[256];
    __shared__ unsigned grp[16];
    __shared__ int chs;
    __shared__ unsigned runs;
    const int t = threadIdx.x;
    const unsigned krem = sel[0];
    unsigned s = 0;
    for (int i = 0; i < bpt; ++i) s += hist[t * bpt + i];
    part[t] = s;
    __syncthreads();
    #pragma unroll
    for (int off = 1; off < 256; off <<= 1) {
        unsigned add = (t >= off) ? part[t - off] : 0u;
        __syncthreads();
        part[t] += add;
        __syncthreads();
    }
    unsigned incl = part[t];
    unsigned excl = incl - s;
    if (excl <= krem && krem < incl) { chs = t; runs = excl; }
    __syncthreads();
    int ch = chs;
    if (t < bpt) grp[t] = hist[ch * bpt + t];
    __syncthreads();
    if (t == 0) {
        unsigned r2 = runs; int bsel = ch * bpt;
        for (int j = 0; j < bpt; ++j) {
            unsigned h = grp[j];
            if (r2 + h > krem) { bsel = ch * bpt + j; break; }
            r2 += h;
        }
        sel[0] = krem - r2;
        unsigned pref = (sel[1] << bits) | (unsigned)bsel;
        sel[1] = pref;
        if (final_stage) {
            unsigned fb = (pref & 0x80000000u) ? (pref ^ 0x80000000u) : ~pref;
            ((float*)sel)[2] = __uint_as_float(fb);
        }
    }
}

// ---------- K2: threshold + 7x7 maxpool (separable) + binarize*R ----------
__launch_bounds__(256, 7)
__global__ void harris_out(const float* __restrict__ R, const unsigned* __restrict__ sel,
                           float* __restrict__ out) {
    __shared__ float SR[38 * 72];   // raw R with halo 3, OOB = -inf
    __shared__ float SM[38 * 64];   // horizontal thr-max
    const float med = ((const float*)sel)[2];
    const int tid = threadIdx.x;
    const int x0 = blockIdx.x * 64, y0 = blockIdx.y * 32, b = blockIdx.z;
    const float* Rb = R + (size_t)b * IMH * IMW;

    for (int i = tid; i < 38 * 70; i += 256) {
        int r = i / 70, c = i - r * 70;
        int gy = y0 - 3 + r, gx = x0 - 3 + c;
        float v = -INFINITY;
        if ((unsigned)gy < (unsigned)IMH && (unsigned)gx < (unsigned)IMW) v = Rb[(size_t)gy * IMW + gx];
        SR[r * 72 + c] = v;
    }
    __syncthreads();

    for (int i = tid; i < 38 * 64; i += 256) {
        int r = i >> 6, c = i & 63;
        const float* p = SR + r * 72 + c;
        float m = -INFINITY;
        #pragma unroll
        for (int d = 0; d < 7; ++d) {
            float v = p[d];
            float t = (v < med) ? ((v == -INFINITY) ? -INFINITY : 0.0f) : v;  // thr; OOB stays -inf
            m = fmaxf(m, t);
        }
        SM[i] = m;
    }
    __syncthreads();

    const int lx = tid & 63, rb = tid >> 6;
    float* ob = out + (size_t)b * IMH * IMW;
    #pragma unroll
    for (int k = 0; k < 8; ++k) {
        int r = rb + 4 * k;
        float pooled = -INFINITY;
        #pragma unroll
        for (int d = 0; d < 7; ++d) pooled = fmaxf(pooled, SM[(r + d) * 64 + lx]);
        float v = SR[(r + 3) * 72 + (lx + 3)];       // center raw R
        float t = (v < med) ? 0.0f : v;
        ob[(size_t)(y0 + r) * IMW + (x0 + lx)] = (t == pooled) ? v : 0.0f;
    }
}

extern "C" void kernel_launch(void* const* d_in, const int* in_sizes, int n_in,
                              void* d_out, int out_size, void* d_ws, size_t ws_size,
                              hipStream_t stream) {
    const float* x = (const float*)d_in[0];
    float* out = (float*)d_out;

    // ws layout: R (64MB) | h1[4096] | h2[4096] | h3[256] | sel[8]
    const size_t needed = (size_t)NPIX * 4 + (4096 + 4096 + 256 + 8) * 4;
    if (ws_size < needed) return;
    float* R = (float*)d_ws;
    unsigned* hbase = (unsigned*)((char*)d_ws + (size_t)NPIX * 4);
    unsigned* h1 = hbase;
    unsigned* h2 = hbase + 4096;
    unsigned* h3 = hbase + 8192;
    unsigned* sel = hbase + 8448;

    zero_kernel<<<(8456 + 255) / 256, 256, 0, stream>>>(hbase, 8456, 8448, KSEL);

    dim3 tgrid(IMW / 64, IMH / 32, NB);
    harris_R<<<tgrid, 256, 0, stream>>>(x, R, h1);

    select_kernel<<<1, 256, 0, stream>>>(h1, sel, 16, 12, 0);
    hist2_kernel<<<2048, 256, 0, stream>>>(R, h2, sel);
    select_kernel<<<1, 256, 0, stream>>>(h2, sel, 16, 12, 0);
    hist3_kernel<<<2048, 256, 0, stream>>>(R, h3, sel);
    select_kernel<<<1, 256, 0, stream>>>(h3, sel, 1, 8, 1);

    harris_out<<<tgrid, 256, 0, stream>>>(R, sel, out);
}